// Round 1
// baseline (661.466 us; speedup 1.0000x reference)
//
#include <hip/hip_runtime.h>

typedef __attribute__((ext_vector_type(8))) short short8;
typedef __attribute__((ext_vector_type(4))) float float4v;

#define NB 32
#define NC 512
#define NL 512
#define NH 8
#define NDK 64

__device__ __forceinline__ unsigned short f2b(float f) {
  union { float f; unsigned int u; } v; v.f = f;
  unsigned int r = v.u + 0x7FFFu + ((v.u >> 16) & 1u);
  return (unsigned short)(r >> 16);
}
__device__ __forceinline__ float b2f(unsigned short s) {
  union { unsigned int u; float f; } v; v.u = ((unsigned int)s) << 16;
  return v.f;
}

__global__ __launch_bounds__(256) void cvt_bf16_kernel(const float* __restrict__ in,
                                                       unsigned short* __restrict__ out, int n) {
  int i = blockIdx.x * 256 + threadIdx.x;
  if (i < n) out[i] = f2b(in[i]);
}

// pos-bias (q,k only) + depthwise conv1d(ks=7, pad=3) + dw bias; writes yT (B, L, C) bf16
__global__ __launch_bounds__(256) void dw_kernel(
    const float* __restrict__ q, const float* __restrict__ k, const float* __restrict__ v,
    const float* __restrict__ pos,
    const float* __restrict__ qw, const float* __restrict__ qb,
    const float* __restrict__ kw, const float* __restrict__ kb,
    const float* __restrict__ vw, const float* __restrict__ vb,
    unsigned short* __restrict__ yq, unsigned short* __restrict__ yk,
    unsigned short* __restrict__ yv) {
  int t = blockIdx.z % 3;
  int b = blockIdx.z / 3;
  const float* x   = (t == 0) ? q  : (t == 1) ? k  : v;
  const float* dww = (t == 0) ? qw : (t == 1) ? kw : vw;
  const float* dwb = (t == 0) ? qb : (t == 1) ? kb : vb;
  unsigned short* yT = (t == 0) ? yq : (t == 1) ? yk : yv;
  bool addpos = (t < 2);
  int c0 = blockIdx.y * 64, l0 = blockIdx.x * 64;
  __shared__ float xs[64][73];  // pad 73: 9*cl mod 32 covers all banks (2-way max = free)
  for (int idx = threadIdx.x; idx < 64 * 72; idx += 256) {
    int cl = idx / 72, ll = idx % 72;
    int l = l0 - 3 + ll;
    float val = 0.f;
    if (l >= 0 && l < NL) {
      val = x[((size_t)b * NC + (c0 + cl)) * NL + l];
      if (addpos) val += pos[(size_t)l * NC + (c0 + cl)];
    }
    xs[cl][ll] = val;
  }
  __syncthreads();
  for (int idx = threadIdx.x; idx < 64 * 64; idx += 256) {
    int ll = idx / 64, cl = idx % 64;  // cl fastest -> coalesced store along c
    int c = c0 + cl;
    float acc = dwb[c];
#pragma unroll
    for (int tt = 0; tt < 7; ++tt) acc += xs[cl][ll + tt] * dww[c * 7 + tt];
    yT[((size_t)b * NL + (l0 + ll)) * NC + c] = f2b(acc);
  }
}

// Z[b](o,l) = W(o,c) * Y[b](c,l) + bias[o];  Y stored N-major as yT (l, c).
// mode 0: store qT/kT layout (B, H, L, DK);  mode 1: store (B, C, L).
__global__ __launch_bounds__(256) void pw_gemm_kernel(
    const unsigned short* __restrict__ A,   // (512, 512) bf16 row-major (o, c)
    const unsigned short* __restrict__ Bt,  // (B, L, C) bf16
    const float* __restrict__ bias, unsigned short* __restrict__ out, int mode) {
  int n0 = blockIdx.x * 64, m0 = blockIdx.y * 64, b = blockIdx.z;
  int tid = threadIdx.x, wave = tid >> 6, lane = tid & 63, quad = lane >> 4, l15 = lane & 15;
  const unsigned short* Bb = Bt + (size_t)b * NL * NC;
  int mrow = m0 + wave * 16 + l15;
  float4v acc[4] = {{0,0,0,0},{0,0,0,0},{0,0,0,0},{0,0,0,0}};
  for (int ks = 0; ks < 16; ++ks) {
    int kk = ks * 32 + quad * 8;
    short8 a = *(const short8*)(A + (size_t)mrow * 512 + kk);
#pragma unroll
    for (int nt = 0; nt < 4; ++nt) {
      short8 bf = *(const short8*)(Bb + (size_t)(n0 + nt * 16 + l15) * 512 + kk);
      acc[nt] = __builtin_amdgcn_mfma_f32_16x16x32_bf16(a, bf, acc[nt], 0, 0, 0);
    }
  }
  int mb = m0 + wave * 16 + quad * 4;
#pragma unroll
  for (int nt = 0; nt < 4; ++nt) {
    int n = n0 + nt * 16 + l15;
#pragma unroll
    for (int r = 0; r < 4; ++r) {
      int m = mb + r;
      float val = acc[nt][r] + bias[m];
      size_t idx;
      if (mode == 0) idx = (((size_t)b * NH + (m >> 6)) * NL + n) * NDK + (m & 63);
      else           idx = ((size_t)b * NC + m) * NL + n;
      out[idx] = f2b(val);
    }
  }
}

// Fused attention per (b, h, 64-row i-block): S=QK^T/8 -> softmax -> O=V*P^T
__global__ __launch_bounds__(256) void attn_kernel(
    const unsigned short* __restrict__ qT,  // (B,H,L,DK)
    const unsigned short* __restrict__ kT,  // (B,H,L,DK)
    const unsigned short* __restrict__ vv,  // (B,C,L) == (B,H,DK,L)
    unsigned short* __restrict__ AO) {      // (B,C,L)
  int i0 = blockIdx.x * 64, h = blockIdx.y, b = blockIdx.z;
  int tid = threadIdx.x, wave = tid >> 6, lane = tid & 63, quad = lane >> 4, l15 = lane & 15;
  __shared__ __attribute__((aligned(16))) unsigned short Sld[64][520];  // +8 pad: 2-way max
  __shared__ float rinv[64];
  const unsigned short* qh = qT + (size_t)(b * NH + h) * NL * NDK;
  const unsigned short* kh = kT + (size_t)(b * NH + h) * NL * NDK;
  const unsigned short* vh = vv + ((size_t)b * NC + h * NDK) * NL;

  // Phase 1: wave w computes S rows [16w,16w+16) x all 512 j
  int iw = i0 + wave * 16;
  short8 a0 = *(const short8*)(qh + (size_t)(iw + l15) * NDK + quad * 8);
  short8 a1 = *(const short8*)(qh + (size_t)(iw + l15) * NDK + 32 + quad * 8);
  float rowmax[4] = {-1e30f, -1e30f, -1e30f, -1e30f};
  for (int jt = 0; jt < 32; ++jt) {
    int j0 = jt * 16;
    short8 b0 = *(const short8*)(kh + (size_t)(j0 + l15) * NDK + quad * 8);
    short8 b1 = *(const short8*)(kh + (size_t)(j0 + l15) * NDK + 32 + quad * 8);
    float4v acc = {0, 0, 0, 0};
    acc = __builtin_amdgcn_mfma_f32_16x16x32_bf16(a0, b0, acc, 0, 0, 0);
    acc = __builtin_amdgcn_mfma_f32_16x16x32_bf16(a1, b1, acc, 0, 0, 0);
#pragma unroll
    for (int r = 0; r < 4; ++r) {
      float s = acc[r] * 0.125f;  // 1/sqrt(64)
      rowmax[r] = fmaxf(rowmax[r], s);
      Sld[wave * 16 + quad * 4 + r][j0 + l15] = f2b(s);
    }
  }
#pragma unroll
  for (int r = 0; r < 4; ++r)
    for (int m = 1; m < 16; m <<= 1)
      rowmax[r] = fmaxf(rowmax[r], __shfl_xor(rowmax[r], m));

  // Phase 2: exp + row sums (each wave owns its 16 rows)
  float rowsum[4] = {0.f, 0.f, 0.f, 0.f};
  for (int t = 0; t < 32; ++t) {
    int col = l15 + 16 * t;
#pragma unroll
    for (int r = 0; r < 4; ++r) {
      int row = wave * 16 + quad * 4 + r;
      float p = __expf(b2f(Sld[row][col]) - rowmax[r]);
      rowsum[r] += p;
      Sld[row][col] = f2b(p);
    }
  }
#pragma unroll
  for (int r = 0; r < 4; ++r)
    for (int m = 1; m < 16; m <<= 1)
      rowsum[r] += __shfl_xor(rowsum[r], m);
  if (l15 == 0) {
#pragma unroll
    for (int r = 0; r < 4; ++r) rinv[wave * 16 + quad * 4 + r] = 1.0f / rowsum[r];
  }
  __syncthreads();

  // Phase 3: O(d,i) = sum_j V(d,j) P(i,j); wave w handles d in [16w,16w+16), all 64 i
  float4v o[4] = {{0,0,0,0},{0,0,0,0},{0,0,0,0},{0,0,0,0}};
  int dwv = wave * 16;
  for (int ks = 0; ks < 16; ++ks) {
    int kk = ks * 32 + quad * 8;
    short8 a = *(const short8*)(vh + (size_t)(dwv + l15) * NL + kk);
#pragma unroll
    for (int nt = 0; nt < 4; ++nt) {
      short8 bp = *(const short8*)(&Sld[nt * 16 + l15][kk]);
      o[nt] = __builtin_amdgcn_mfma_f32_16x16x32_bf16(a, bp, o[nt], 0, 0, 0);
    }
  }
#pragma unroll
  for (int nt = 0; nt < 4; ++nt) {
    int i = nt * 16 + l15;
    float ri = rinv[i];
#pragma unroll
    for (int r = 0; r < 4; ++r) {
      int d = dwv + quad * 4 + r;
      AO[((size_t)b * NC + h * NDK + d) * NL + i0 + i] = f2b(o[nt][r] * ri);
    }
  }
}

// R[b](i_ch, o) = AO[b](i_ch, p) * proj_w(o, p) + proj_b[o]; fp32 out
__global__ __launch_bounds__(256) void final_gemm_kernel(
    const unsigned short* __restrict__ AO,  // (B, 512, 512) bf16
    const unsigned short* __restrict__ W,   // (512, 512) bf16 (o, p) == N-major
    const float* __restrict__ bias, float* __restrict__ out) {
  int n0 = blockIdx.x * 64, m0 = blockIdx.y * 64, b = blockIdx.z;
  int tid = threadIdx.x, wave = tid >> 6, lane = tid & 63, quad = lane >> 4, l15 = lane & 15;
  const unsigned short* Ab = AO + (size_t)b * 512 * 512;
  int mrow = m0 + wave * 16 + l15;
  float4v acc[4] = {{0,0,0,0},{0,0,0,0},{0,0,0,0},{0,0,0,0}};
  for (int ks = 0; ks < 16; ++ks) {
    int kk = ks * 32 + quad * 8;
    short8 a = *(const short8*)(Ab + (size_t)mrow * 512 + kk);
#pragma unroll
    for (int nt = 0; nt < 4; ++nt) {
      short8 bf = *(const short8*)(W + (size_t)(n0 + nt * 16 + l15) * 512 + kk);
      acc[nt] = __builtin_amdgcn_mfma_f32_16x16x32_bf16(a, bf, acc[nt], 0, 0, 0);
    }
  }
  int mb = m0 + wave * 16 + quad * 4;
#pragma unroll
  for (int nt = 0; nt < 4; ++nt) {
    int n = n0 + nt * 16 + l15;
    float bn = bias[n];
#pragma unroll
    for (int r = 0; r < 4; ++r) {
      int m = mb + r;
      out[((size_t)b * 512 + m) * 512 + n] = acc[nt][r] + bn;
    }
  }
}

extern "C" void kernel_launch(void* const* d_in, const int* in_sizes, int n_in,
                              void* d_out, int out_size, void* d_ws, size_t ws_size,
                              hipStream_t stream) {
  (void)in_sizes; (void)n_in; (void)out_size; (void)ws_size;
  const float* query  = (const float*)d_in[0];
  const float* key    = (const float*)d_in[1];
  const float* value  = (const float*)d_in[2];
  const float* pos    = (const float*)d_in[3];
  const float* proj_w = (const float*)d_in[4];
  const float* proj_b = (const float*)d_in[5];
  const float* q_dw_w = (const float*)d_in[6];
  const float* q_dw_b = (const float*)d_in[7];
  const float* q_pw_w = (const float*)d_in[8];
  const float* q_pw_b = (const float*)d_in[9];
  const float* k_dw_w = (const float*)d_in[10];
  const float* k_dw_b = (const float*)d_in[11];
  const float* k_pw_w = (const float*)d_in[12];
  const float* k_pw_b = (const float*)d_in[13];
  const float* v_dw_w = (const float*)d_in[14];
  const float* v_dw_b = (const float*)d_in[15];
  const float* v_pw_w = (const float*)d_in[16];
  const float* v_pw_b = (const float*)d_in[17];

  char* ws = (char*)d_ws;
  const size_t WMAT = (size_t)512 * 512 * 2;        // 512 KB
  const size_t TEN  = (size_t)NB * NC * NL * 2;     // 16 MB
  unsigned short* wq  = (unsigned short*)(ws);
  unsigned short* wk  = (unsigned short*)(ws + WMAT);
  unsigned short* wv  = (unsigned short*)(ws + 2 * WMAT);
  unsigned short* wp  = (unsigned short*)(ws + 3 * WMAT);
  unsigned short* yq  = (unsigned short*)(ws + 4 * WMAT);
  unsigned short* yk  = (unsigned short*)(ws + 4 * WMAT + TEN);
  unsigned short* yv  = (unsigned short*)(ws + 4 * WMAT + 2 * TEN);
  unsigned short* qT  = (unsigned short*)(ws + 4 * WMAT + 3 * TEN);
  unsigned short* kT  = (unsigned short*)(ws + 4 * WMAT + 4 * TEN);
  unsigned short* vvb = (unsigned short*)(ws + 4 * WMAT + 5 * TEN);
  unsigned short* AO  = yq;  // yq fully consumed by pw(q) before attention writes

  const int nW = 512 * 512;
  cvt_bf16_kernel<<<dim3(nW / 256), 256, 0, stream>>>(q_pw_w, wq, nW);
  cvt_bf16_kernel<<<dim3(nW / 256), 256, 0, stream>>>(k_pw_w, wk, nW);
  cvt_bf16_kernel<<<dim3(nW / 256), 256, 0, stream>>>(v_pw_w, wv, nW);
  cvt_bf16_kernel<<<dim3(nW / 256), 256, 0, stream>>>(proj_w, wp, nW);

  dw_kernel<<<dim3(8, 8, NB * 3), 256, 0, stream>>>(
      query, key, value, pos, q_dw_w, q_dw_b, k_dw_w, k_dw_b, v_dw_w, v_dw_b, yq, yk, yv);

  pw_gemm_kernel<<<dim3(8, 8, NB), 256, 0, stream>>>(wq, yq, q_pw_b, qT, 0);
  pw_gemm_kernel<<<dim3(8, 8, NB), 256, 0, stream>>>(wk, yk, k_pw_b, kT, 0);
  pw_gemm_kernel<<<dim3(8, 8, NB), 256, 0, stream>>>(wv, yv, v_pw_b, vvb, 1);

  attn_kernel<<<dim3(8, 8, NB), 256, 0, stream>>>(qT, kT, vvb, AO);

  final_gemm_kernel<<<dim3(8, 8, NB), 256, 0, stream>>>(AO, wp, proj_b, (float*)d_out);
}

// Round 2
// 342.397 us; speedup vs baseline: 1.9319x; 1.9319x over previous
//
#include <hip/hip_runtime.h>

typedef __attribute__((ext_vector_type(8))) short short8;
typedef __attribute__((ext_vector_type(4))) float float4v;
typedef __attribute__((ext_vector_type(4))) unsigned short ushort4v;

#define NB 32
#define NC 512
#define NL 512
#define NH 8
#define NDK 64

__device__ __forceinline__ unsigned short f2b(float f) {
  union { float f; unsigned int u; } v; v.f = f;
  unsigned int r = v.u + 0x7FFFu + ((v.u >> 16) & 1u);
  return (unsigned short)(r >> 16);
}

__device__ __forceinline__ void gld16(const void* g, void* l) {
  __builtin_amdgcn_global_load_lds(
      (const __attribute__((address_space(1))) unsigned int*)g,
      (__attribute__((address_space(3))) unsigned int*)l, 16, 0, 0);
}

// ---- fp32 -> bf16 weight conversion, 4 matrices in one launch --------------
__global__ __launch_bounds__(256) void cvt4_kernel(
    const float* __restrict__ a, const float* __restrict__ b,
    const float* __restrict__ c, const float* __restrict__ d,
    unsigned short* __restrict__ oa, unsigned short* __restrict__ ob,
    unsigned short* __restrict__ oc, unsigned short* __restrict__ od) {
  int m = blockIdx.y;
  const float* src = (m == 0) ? a : (m == 1) ? b : (m == 2) ? c : d;
  unsigned short* dst = (m == 0) ? oa : (m == 1) ? ob : (m == 2) ? oc : od;
  int i = (blockIdx.x * 256 + threadIdx.x) * 4;
  float4v v = *(const float4v*)(src + i);
  ushort4v o;
  o.x = f2b(v.x); o.y = f2b(v.y); o.z = f2b(v.z); o.w = f2b(v.w);
  *(ushort4v*)(dst + i) = o;
}

// ---- pos-bias (q,k) + depthwise conv(7) + bias; writes yT (B, L, C) bf16 ---
__global__ __launch_bounds__(256) void dw_kernel(
    const float* __restrict__ q, const float* __restrict__ k, const float* __restrict__ v,
    const float* __restrict__ pos,
    const float* __restrict__ qw, const float* __restrict__ qb,
    const float* __restrict__ kw, const float* __restrict__ kb,
    const float* __restrict__ vw, const float* __restrict__ vb,
    unsigned short* __restrict__ yq, unsigned short* __restrict__ yk,
    unsigned short* __restrict__ yv) {
  int z = blockIdx.z;
  int t = z >> 5, b = z & 31;
  const float* x   = (t == 0) ? q  : (t == 1) ? k  : v;
  const float* dww = (t == 0) ? qw : (t == 1) ? kw : vw;
  const float* dwb = (t == 0) ? qb : (t == 1) ? kb : vb;
  unsigned short* yT = (t == 0) ? yq : (t == 1) ? yk : yv;
  int c0 = blockIdx.y * 64, l0 = blockIdx.x * 64;
  __shared__ float xs[64 * 97];  // row stride 97 -> bank spread
  // stage x: window l0-16 .. l0+79 (96 aligned floats) per channel row
#pragma unroll
  for (int it = 0; it < 6; ++it) {
    int idx = threadIdx.x + 256 * it;  // 0..1535
    int row = idx / 24, f4 = idx % 24;
    int l = l0 - 16 + f4 * 4;
    const float* px = x + ((size_t)b * NC + c0 + row) * NL + l;
    float v0 = 0.f, v1 = 0.f, v2 = 0.f, v3 = 0.f;
    if (l >= 0 && l + 3 < NL) {
      float4v vv = *(const float4v*)px;
      v0 = vv.x; v1 = vv.y; v2 = vv.z; v3 = vv.w;
    } else {
      if (l + 0 >= 0 && l + 0 < NL) v0 = px[0];
      if (l + 1 >= 0 && l + 1 < NL) v1 = px[1];
      if (l + 2 >= 0 && l + 2 < NL) v2 = px[2];
      if (l + 3 >= 0 && l + 3 < NL) v3 = px[3];
    }
    float* xr = xs + row * 97 + f4 * 4;
    xr[0] = v0; xr[1] = v1; xr[2] = v2; xr[3] = v3;
  }
  __syncthreads();
  if (t < 2) {  // add pos bias, c-coalesced
    for (int idx = threadIdx.x; idx < 70 * 64; idx += 256) {
      int ll = idx >> 6, cl = idx & 63;
      int l = l0 - 3 + ll;
      if (l >= 0 && l < NL) xs[cl * 97 + 13 + ll] += pos[(size_t)l * NC + c0 + cl];
    }
  }
  __syncthreads();
  // each thread owns a fixed channel pair, 8 consecutive l outputs
  int cp = threadIdx.x & 31;
  int llb = (threadIdx.x >> 5) * 8;
  int c = c0 + 2 * cp;
  float w0[7], w1[7];
#pragma unroll
  for (int tt = 0; tt < 7; ++tt) { w0[tt] = dww[c * 7 + tt]; w1[tt] = dww[(c + 1) * 7 + tt]; }
  float b0v = dwb[c], b1v = dwb[c + 1];
  float win0[14], win1[14];
#pragma unroll
  for (int j = 0; j < 14; ++j) {
    win0[j] = xs[(2 * cp) * 97 + 13 + llb + j];
    win1[j] = xs[(2 * cp + 1) * 97 + 13 + llb + j];
  }
#pragma unroll
  for (int it = 0; it < 8; ++it) {
    float a0 = b0v, a1 = b1v;
#pragma unroll
    for (int tt = 0; tt < 7; ++tt) { a0 += win0[it + tt] * w0[tt]; a1 += win1[it + tt] * w1[tt]; }
    unsigned int packed = (unsigned int)f2b(a0) | ((unsigned int)f2b(a1) << 16);
    *(unsigned int*)(yT + ((size_t)b * NL + l0 + llb + it) * NC + c) = packed;
  }
}

// ---- shared 128x128 MFMA GEMM core: C = A(M,K) x B(N,K)^T, K=512 -----------
__device__ __forceinline__ void gemm_core_128(
    const unsigned short* __restrict__ A, const unsigned short* __restrict__ B,
    unsigned short* lA, unsigned short* lB, float4v acc[4][4], int m0, int n0) {
  int tid = threadIdx.x;
  int lane = tid & 63, quad = lane >> 4, l15 = lane & 15;
  int wave = tid >> 6, wr = wave >> 1, wc = wave & 1;
  int c0 = tid, c1 = tid + 256;
  const unsigned short* gA0 = A + (size_t)(m0 + (c0 >> 2)) * 512 + (c0 & 3) * 8;
  const unsigned short* gA1 = A + (size_t)(m0 + (c1 >> 2)) * 512 + (c1 & 3) * 8;
  const unsigned short* gB0 = B + (size_t)(n0 + (c0 >> 2)) * 512 + (c0 & 3) * 8;
  const unsigned short* gB1 = B + (size_t)(n0 + (c1 >> 2)) * 512 + (c1 & 3) * 8;
  unsigned short* dA0 = lA + c0 * 8;
  unsigned short* dA1 = lA + c1 * 8;
  unsigned short* dB0 = lB + c0 * 8;
  unsigned short* dB1 = lB + c1 * 8;
  for (int k0 = 0; k0 < 512; k0 += 32) {
    gld16(gA0 + k0, dA0); gld16(gA1 + k0, dA1);
    gld16(gB0 + k0, dB0); gld16(gB1 + k0, dB1);
    __syncthreads();
    short8 af[4], bf[4];
#pragma unroll
    for (int mt = 0; mt < 4; ++mt)
      af[mt] = *(const short8*)(lA + (wr * 64 + mt * 16 + l15) * 32 + quad * 8);
#pragma unroll
    for (int nt = 0; nt < 4; ++nt)
      bf[nt] = *(const short8*)(lB + (wc * 64 + nt * 16 + l15) * 32 + quad * 8);
#pragma unroll
    for (int mt = 0; mt < 4; ++mt)
#pragma unroll
      for (int nt = 0; nt < 4; ++nt)
        acc[mt][nt] = __builtin_amdgcn_mfma_f32_16x16x32_bf16(af[mt], bf[nt], acc[mt][nt], 0, 0, 0);
    __syncthreads();
  }
}

// ---- fused pointwise GEMMs for q,k,v ---------------------------------------
__global__ __launch_bounds__(256) void pw_gemm_kernel(
    const unsigned short* __restrict__ wqm, const unsigned short* __restrict__ wkm,
    const unsigned short* __restrict__ wvm,
    const unsigned short* __restrict__ yq, const unsigned short* __restrict__ yk,
    const unsigned short* __restrict__ yv,
    const float* __restrict__ qb, const float* __restrict__ kb, const float* __restrict__ vb,
    unsigned short* __restrict__ qT, unsigned short* __restrict__ kT,
    unsigned short* __restrict__ vvo) {
  int z = blockIdx.z, t = z >> 5, b = z & 31;
  const unsigned short* W = (t == 0) ? wqm : (t == 1) ? wkm : wvm;
  const unsigned short* Y = ((t == 0) ? yq : (t == 1) ? yk : yv) + (size_t)b * NL * NC;
  const float* bias = (t == 0) ? qb : (t == 1) ? kb : vb;
  unsigned short* out = (t == 0) ? qT : (t == 1) ? kT : vvo;
  __shared__ __attribute__((aligned(16))) unsigned short lA[128 * 32];
  __shared__ __attribute__((aligned(16))) unsigned short lB[128 * 32];
  int m0 = blockIdx.y * 128, n0 = blockIdx.x * 128;
  float4v acc[4][4];
#pragma unroll
  for (int i = 0; i < 4; ++i)
#pragma unroll
    for (int j = 0; j < 4; ++j) acc[i][j] = (float4v){0.f, 0.f, 0.f, 0.f};
  gemm_core_128(W, Y, lA, lB, acc, m0, n0);
  int lane = threadIdx.x & 63, quad = lane >> 4, l15 = lane & 15;
  int wave = threadIdx.x >> 6, wr = wave >> 1, wc = wave & 1;
#pragma unroll
  for (int mt = 0; mt < 4; ++mt)
#pragma unroll
    for (int nt = 0; nt < 4; ++nt) {
      int n = n0 + wc * 64 + nt * 16 + l15;
#pragma unroll
      for (int r = 0; r < 4; ++r) {
        int m = m0 + wr * 64 + mt * 16 + quad * 4 + r;
        float val = acc[mt][nt][r] + bias[m];
        size_t idx = (t < 2) ? ((((size_t)b * NH + (m >> 6)) * NL + n) * NDK + (m & 63))
                             : (((size_t)b * NC + m) * NL + n);
        out[idx] = f2b(val);
      }
    }
}

// ---- flash attention: j-tiles of 64, K staged in LDS, online softmax -------
__global__ __launch_bounds__(256) void attn_kernel(
    const unsigned short* __restrict__ qT,  // (B,H,L,DK)
    const unsigned short* __restrict__ kT,  // (B,H,L,DK)
    const unsigned short* __restrict__ vv,  // (B,C,L)
    unsigned short* __restrict__ AO) {      // (B,C,L)
  int i0 = blockIdx.x * 64, h = blockIdx.y, b = blockIdx.z;
  int tid = threadIdx.x, wave = tid >> 6, lane = tid & 63, quad = lane >> 4, l15 = lane & 15;
  __shared__ __attribute__((aligned(16))) unsigned short K0[64 * 32];  // j x d(0..31)
  __shared__ __attribute__((aligned(16))) unsigned short K1[64 * 32];  // j x d(32..63)
  __shared__ __attribute__((aligned(16))) unsigned short Pt[64 * 64];  // i x j (chunk-swizzled)
  __shared__ float alpha_s[64];
  __shared__ float linv_s[64];
  const unsigned short* qh = qT + (size_t)(b * NH + h) * NL * NDK;
  const unsigned short* kh = kT + (size_t)(b * NH + h) * NL * NDK;
  const unsigned short* vh = vv + ((size_t)b * NC + h * NDK) * NL;
  int iw = i0 + wave * 16;
  short8 a0 = *(const short8*)(qh + (size_t)(iw + l15) * NDK + quad * 8);
  short8 a1 = *(const short8*)(qh + (size_t)(iw + l15) * NDK + 32 + quad * 8);
  int dwv = wave * 16;
  const unsigned short* vrow = vh + (size_t)(dwv + l15) * NL;
  const unsigned short* gk = kh + (size_t)(tid >> 2) * NDK + (tid & 3) * 8;
  unsigned short* dK0 = K0 + tid * 8;
  unsigned short* dK1 = K1 + tid * 8;
  int prow = wave * 16 + quad * 4;
  float m_run[4] = {-1e30f, -1e30f, -1e30f, -1e30f};
  float l_run[4] = {0.f, 0.f, 0.f, 0.f};
  float4v o[4];
#pragma unroll
  for (int i = 0; i < 4; ++i) o[i] = (float4v){0.f, 0.f, 0.f, 0.f};

  for (int jt = 0; jt < 8; ++jt) {
    int j0 = jt * 64;
    gld16(gk + (size_t)j0 * NDK, dK0);
    gld16(gk + (size_t)j0 * NDK + 32, dK1);
    __syncthreads();
    // S tile: 16 i-rows (this wave) x 64 j
    float4v s[4];
#pragma unroll
    for (int n4 = 0; n4 < 4; ++n4) {
      short8 kb0 = *(const short8*)(K0 + (n4 * 16 + l15) * 32 + quad * 8);
      short8 kb1 = *(const short8*)(K1 + (n4 * 16 + l15) * 32 + quad * 8);
      float4v acc = {0.f, 0.f, 0.f, 0.f};
      acc = __builtin_amdgcn_mfma_f32_16x16x32_bf16(a0, kb0, acc, 0, 0, 0);
      acc = __builtin_amdgcn_mfma_f32_16x16x32_bf16(a1, kb1, acc, 0, 0, 0);
      s[n4] = acc;
    }
#pragma unroll
    for (int n4 = 0; n4 < 4; ++n4)
#pragma unroll
      for (int r = 0; r < 4; ++r) s[n4][r] *= 0.125f;
    float al[4];
#pragma unroll
    for (int r = 0; r < 4; ++r) {
      float mx = fmaxf(fmaxf(s[0][r], s[1][r]), fmaxf(s[2][r], s[3][r]));
      mx = fmaxf(mx, __shfl_xor(mx, 1));
      mx = fmaxf(mx, __shfl_xor(mx, 2));
      mx = fmaxf(mx, __shfl_xor(mx, 4));
      mx = fmaxf(mx, __shfl_xor(mx, 8));
      float mn = fmaxf(m_run[r], mx);
      al[r] = __expf(m_run[r] - mn);
      m_run[r] = mn;
      float sum = 0.f;
#pragma unroll
      for (int n4 = 0; n4 < 4; ++n4) {
        float p = __expf(s[n4][r] - mn);
        s[n4][r] = p;
        sum += p;
      }
      sum += __shfl_xor(sum, 1);
      sum += __shfl_xor(sum, 2);
      sum += __shfl_xor(sum, 4);
      sum += __shfl_xor(sum, 8);
      l_run[r] = l_run[r] * al[r] + sum;
    }
    // write P (bf16, XOR chunk swizzle) + alpha
#pragma unroll
    for (int n4 = 0; n4 < 4; ++n4)
#pragma unroll
      for (int r = 0; r < 4; ++r) {
        int row = prow + r, col = n4 * 16 + l15;
        Pt[row * 64 + ((((col >> 3) ^ (row & 7)) << 3) | (col & 7))] = f2b(s[n4][r]);
      }
    if (l15 == 0) {
#pragma unroll
      for (int r = 0; r < 4; ++r) alpha_s[prow + r] = al[r];
    }
    __syncthreads();
    // PV: O(d,i) += V(d,j) P(i,j); this wave owns d-slice [16w,16w+16)
    short8 av0 = *(const short8*)(vrow + j0 + quad * 8);
    short8 av1 = *(const short8*)(vrow + j0 + 32 + quad * 8);
#pragma unroll
    for (int nt = 0; nt < 4; ++nt) {
      int rI = nt * 16 + l15;
      float aR = alpha_s[rI];
      o[nt][0] *= aR; o[nt][1] *= aR; o[nt][2] *= aR; o[nt][3] *= aR;
      short8 pb0 = *(const short8*)(Pt + rI * 64 + ((quad ^ (rI & 7)) << 3));
      short8 pb1 = *(const short8*)(Pt + rI * 64 + (((quad + 4) ^ (rI & 7)) << 3));
      o[nt] = __builtin_amdgcn_mfma_f32_16x16x32_bf16(av0, pb0, o[nt], 0, 0, 0);
      o[nt] = __builtin_amdgcn_mfma_f32_16x16x32_bf16(av1, pb1, o[nt], 0, 0, 0);
    }
  }
  if (l15 == 0) {
#pragma unroll
    for (int r = 0; r < 4; ++r) linv_s[prow + r] = 1.0f / l_run[r];
  }
  __syncthreads();
#pragma unroll
  for (int nt = 0; nt < 4; ++nt) {
    float li = linv_s[nt * 16 + l15];
#pragma unroll
    for (int r = 0; r < 4; ++r) {
      int d = dwv + quad * 4 + r;
      AO[((size_t)b * NC + h * NDK + d) * NL + i0 + nt * 16 + l15] = f2b(o[nt][r] * li);
    }
  }
}

// ---- final projection GEMM (fp32 out) --------------------------------------
__global__ __launch_bounds__(256) void final_gemm_kernel(
    const unsigned short* __restrict__ AO, const unsigned short* __restrict__ W,
    const float* __restrict__ bias, float* __restrict__ out) {
  int b = blockIdx.z;
  __shared__ __attribute__((aligned(16))) unsigned short lA[128 * 32];
  __shared__ __attribute__((aligned(16))) unsigned short lB[128 * 32];
  int m0 = blockIdx.y * 128, n0 = blockIdx.x * 128;
  float4v acc[4][4];
#pragma unroll
  for (int i = 0; i < 4; ++i)
#pragma unroll
    for (int j = 0; j < 4; ++j) acc[i][j] = (float4v){0.f, 0.f, 0.f, 0.f};
  gemm_core_128(AO + (size_t)b * 512 * 512, W, lA, lB, acc, m0, n0);
  int lane = threadIdx.x & 63, quad = lane >> 4, l15 = lane & 15;
  int wave = threadIdx.x >> 6, wr = wave >> 1, wc = wave & 1;
#pragma unroll
  for (int mt = 0; mt < 4; ++mt)
#pragma unroll
    for (int nt = 0; nt < 4; ++nt) {
      int n = n0 + wc * 64 + nt * 16 + l15;
      float bn = bias[n];
#pragma unroll
      for (int r = 0; r < 4; ++r) {
        int m = m0 + wr * 64 + mt * 16 + quad * 4 + r;
        out[((size_t)b * 512 + m) * 512 + n] = acc[mt][nt][r] + bn;
      }
    }
}

extern "C" void kernel_launch(void* const* d_in, const int* in_sizes, int n_in,
                              void* d_out, int out_size, void* d_ws, size_t ws_size,
                              hipStream_t stream) {
  (void)in_sizes; (void)n_in; (void)out_size; (void)ws_size;
  const float* query  = (const float*)d_in[0];
  const float* key    = (const float*)d_in[1];
  const float* value  = (const float*)d_in[2];
  const float* pos    = (const float*)d_in[3];
  const float* proj_w = (const float*)d_in[4];
  const float* proj_b = (const float*)d_in[5];
  const float* q_dw_w = (const float*)d_in[6];
  const float* q_dw_b = (const float*)d_in[7];
  const float* q_pw_w = (const float*)d_in[8];
  const float* q_pw_b = (const float*)d_in[9];
  const float* k_dw_w = (const float*)d_in[10];
  const float* k_dw_b = (const float*)d_in[11];
  const float* k_pw_w = (const float*)d_in[12];
  const float* k_pw_b = (const float*)d_in[13];
  const float* v_dw_w = (const float*)d_in[14];
  const float* v_dw_b = (const float*)d_in[15];
  const float* v_pw_w = (const float*)d_in[16];
  const float* v_pw_b = (const float*)d_in[17];

  char* ws = (char*)d_ws;
  const size_t WMAT = (size_t)512 * 512 * 2;     // 512 KB
  const size_t TEN  = (size_t)NB * NC * NL * 2;  // 16 MB
  unsigned short* wq  = (unsigned short*)(ws);
  unsigned short* wk  = (unsigned short*)(ws + WMAT);
  unsigned short* wv  = (unsigned short*)(ws + 2 * WMAT);
  unsigned short* wp  = (unsigned short*)(ws + 3 * WMAT);
  unsigned short* yq  = (unsigned short*)(ws + 4 * WMAT);
  unsigned short* yk  = (unsigned short*)(ws + 4 * WMAT + TEN);
  unsigned short* yv  = (unsigned short*)(ws + 4 * WMAT + 2 * TEN);
  unsigned short* qT  = (unsigned short*)(ws + 4 * WMAT + 3 * TEN);
  unsigned short* kT  = (unsigned short*)(ws + 4 * WMAT + 4 * TEN);
  unsigned short* vvb = (unsigned short*)(ws + 4 * WMAT + 5 * TEN);
  unsigned short* AO  = yq;  // yq fully consumed by pw(q) before attention writes

  cvt4_kernel<<<dim3(256, 4), 256, 0, stream>>>(q_pw_w, k_pw_w, v_pw_w, proj_w, wq, wk, wv, wp);

  dw_kernel<<<dim3(8, 8, 96), 256, 0, stream>>>(
      query, key, value, pos, q_dw_w, q_dw_b, k_dw_w, k_dw_b, v_dw_w, v_dw_b, yq, yk, yv);

  pw_gemm_kernel<<<dim3(4, 4, 96), 256, 0, stream>>>(
      wq, wk, wv, yq, yk, yv, q_pw_b, k_pw_b, v_pw_b, qT, kT, vvb);

  attn_kernel<<<dim3(8, 8, 32), 256, 0, stream>>>(qT, kT, vvb, AO);

  final_gemm_kernel<<<dim3(4, 4, 32), 256, 0, stream>>>(AO, wp, proj_b, (float*)d_out);
}

// Round 3
// 311.522 us; speedup vs baseline: 2.1233x; 1.0991x over previous
//
#include <hip/hip_runtime.h>

typedef __attribute__((ext_vector_type(8))) short short8;
typedef __attribute__((ext_vector_type(4))) float float4v;
typedef __attribute__((ext_vector_type(4))) unsigned short ushort4v;

#define NB 32
#define NC 512
#define NL 512
#define NH 8
#define NDK 64

__device__ __forceinline__ unsigned short f2b(float f) {
  union { float f; unsigned int u; } v; v.f = f;
  unsigned int r = v.u + 0x7FFFu + ((v.u >> 16) & 1u);
  return (unsigned short)(r >> 16);
}

__device__ __forceinline__ void gld16(const void* g, void* l) {
  __builtin_amdgcn_global_load_lds(
      (const __attribute__((address_space(1))) unsigned int*)g,
      (__attribute__((address_space(3))) unsigned int*)l, 16, 0, 0);
}

__device__ __forceinline__ float4v bmfma(short8 a, short8 b, float4v c) {
  return __builtin_amdgcn_mfma_f32_16x16x32_bf16(a, b, c, 0, 0, 0);
}

// ---- fp32 -> bf16 weight conversion, 4 matrices in one launch --------------
__global__ __launch_bounds__(256) void cvt4_kernel(
    const float* __restrict__ a, const float* __restrict__ b,
    const float* __restrict__ c, const float* __restrict__ d,
    unsigned short* __restrict__ oa, unsigned short* __restrict__ ob,
    unsigned short* __restrict__ oc, unsigned short* __restrict__ od) {
  int m = blockIdx.y;
  const float* src = (m == 0) ? a : (m == 1) ? b : (m == 2) ? c : d;
  unsigned short* dst = (m == 0) ? oa : (m == 1) ? ob : (m == 2) ? oc : od;
  int i = (blockIdx.x * 256 + threadIdx.x) * 4;
  float4v v = *(const float4v*)(src + i);
  ushort4v o;
  o.x = f2b(v.x); o.y = f2b(v.y); o.z = f2b(v.z); o.w = f2b(v.w);
  *(ushort4v*)(dst + i) = o;
}

// ---- posconv: conv(pos, dw_w) + dw_b, batch-independent; out (L,C) fp32 ----
__global__ __launch_bounds__(256) void posconv_kernel(
    const float* __restrict__ pos,
    const float* __restrict__ qw, const float* __restrict__ qb,
    const float* __restrict__ kw, const float* __restrict__ kb,
    float* __restrict__ pq, float* __restrict__ pk) {
  int t = blockIdx.y, l = blockIdx.x;
  const float* w  = t ? kw : qw;
  const float* bb = t ? kb : qb;
  float* outp = t ? pk : pq;
  for (int c = threadIdx.x; c < NC; c += 256) {
    float acc = bb[c];
#pragma unroll
    for (int tt = 0; tt < 7; ++tt) {
      int ll = l + tt - 3;
      if (ll >= 0 && ll < NL) acc += pos[(size_t)ll * NC + c] * w[c * 7 + tt];
    }
    outp[(size_t)l * NC + c] = acc;
  }
}

// ---- depthwise conv(7); posconv(+bias) added for q,k; writes yT (B,L,C) ----
__global__ __launch_bounds__(256) void dw_kernel(
    const float* __restrict__ q, const float* __restrict__ k, const float* __restrict__ v,
    const float* __restrict__ pq, const float* __restrict__ pk,
    const float* __restrict__ qw, const float* __restrict__ kw, const float* __restrict__ vw,
    const float* __restrict__ vb,
    unsigned short* __restrict__ yq, unsigned short* __restrict__ yk,
    unsigned short* __restrict__ yv) {
  int z = blockIdx.z;
  int t = z >> 5, b = z & 31;
  const float* x   = (t == 0) ? q  : (t == 1) ? k  : v;
  const float* dww = (t == 0) ? qw : (t == 1) ? kw : vw;
  const float* pcv = (t == 0) ? pq : pk;  // only used when t<2
  unsigned short* yT = (t == 0) ? yq : (t == 1) ? yk : yv;
  int c0 = blockIdx.y * 64, l0 = blockIdx.x * 64;
  int tid = threadIdx.x;
  __shared__ __attribute__((aligned(16))) float xs[64 * 100];  // 25 x 16B rows (odd -> b128 conflict-free)
  // stage window l0-16 .. l0+80 (96 floats) per channel row
#pragma unroll
  for (int it = 0; it < 6; ++it) {
    int idx = tid + 256 * it;  // 0..1535
    int row = idx / 24, f4 = idx - row * 24;
    int l = l0 - 16 + f4 * 4;
    const float* px = x + ((size_t)b * NC + c0 + row) * NL + l;
    float v0 = 0.f, v1 = 0.f, v2 = 0.f, v3 = 0.f;
    if (l >= 0 && l + 3 < NL) {
      float4v vv = *(const float4v*)px;
      v0 = vv.x; v1 = vv.y; v2 = vv.z; v3 = vv.w;
    } else {
      if (l + 0 >= 0 && l + 0 < NL) v0 = px[0];
      if (l + 1 >= 0 && l + 1 < NL) v1 = px[1];
      if (l + 2 >= 0 && l + 2 < NL) v2 = px[2];
      if (l + 3 >= 0 && l + 3 < NL) v3 = px[3];
    }
    float* xr = xs + row * 100 + f4 * 4;
    xr[0] = v0; xr[1] = v1; xr[2] = v2; xr[3] = v3;
  }
  __syncthreads();
  // thread owns channel c = tid&63, 16 outputs llb..llb+15
  int cl = tid & 63;
  int llb = (tid >> 6) * 16;
  int c = c0 + cl;
  float w[24];
  const float4v* xr = (const float4v*)(xs + cl * 100 + llb + 12);  // = x[l0+llb-4 ..)
#pragma unroll
  for (int j = 0; j < 6; ++j) {
    float4v t4 = xr[j];
    w[4 * j] = t4.x; w[4 * j + 1] = t4.y; w[4 * j + 2] = t4.z; w[4 * j + 3] = t4.w;
  }
  float wt[7];
#pragma unroll
  for (int tt = 0; tt < 7; ++tt) wt[tt] = dww[c * 7 + tt];
  float addv[16];
  if (t < 2) {
#pragma unroll
    for (int i = 0; i < 16; ++i) addv[i] = pcv[(size_t)(l0 + llb + i) * NC + c];
  } else {
    float bb = vb[c];
#pragma unroll
    for (int i = 0; i < 16; ++i) addv[i] = bb;
  }
#pragma unroll
  for (int i = 0; i < 16; ++i) {
    float acc = addv[i];
#pragma unroll
    for (int tt = 0; tt < 7; ++tt) acc += w[i + 1 + tt] * wt[tt];
    yT[((size_t)b * NL + l0 + llb + i) * NC + c] = f2b(acc);
  }
}

// ---- 128x128 MFMA GEMM core, BK=64, global-XOR-swizzled staging ------------
// C = A(M,K) x B(N,K)^T, K=512. lA/lB are 128x64 bf16 (16KB each, contiguous).
__device__ __forceinline__ void gemm_core_bk64(
    const unsigned short* __restrict__ A, const unsigned short* __restrict__ B,
    unsigned short* lA, unsigned short* lB, float4v acc[4][4], int m0, int n0) {
  int tid = threadIdx.x;
  int lane = tid & 63, quad = lane >> 4, l15 = lane & 15;
  int wave = tid >> 6, wr = wave >> 1, wc = wave & 1;
  const unsigned short* gA[4];
  const unsigned short* gB[4];
  unsigned short* dA[4];
  unsigned short* dB[4];
#pragma unroll
  for (int i = 0; i < 4; ++i) {
    int cc = tid + 256 * i;            // chunk id 0..1023
    int row = cc >> 3;
    int gc = (cc & 7) ^ (row & 7);     // global-side swizzle
    gA[i] = A + (size_t)(m0 + row) * 512 + gc * 8;
    gB[i] = B + (size_t)(n0 + row) * 512 + gc * 8;
    dA[i] = lA + cc * 8;
    dB[i] = lB + cc * 8;
  }
  for (int k0 = 0; k0 < 512; k0 += 64) {
#pragma unroll
    for (int i = 0; i < 4; ++i) gld16(gA[i] + k0, dA[i]);
#pragma unroll
    for (int i = 0; i < 4; ++i) gld16(gB[i] + k0, dB[i]);
    __syncthreads();
#pragma unroll
    for (int ks = 0; ks < 2; ++ks) {
      int sw = (ks * 4 + quad) ^ (l15 & 7);
      short8 af[4], bf[4];
#pragma unroll
      for (int mt = 0; mt < 4; ++mt)
        af[mt] = *(const short8*)(lA + (wr * 64 + mt * 16 + l15) * 64 + sw * 8);
#pragma unroll
      for (int nt = 0; nt < 4; ++nt)
        bf[nt] = *(const short8*)(lB + (wc * 64 + nt * 16 + l15) * 64 + sw * 8);
#pragma unroll
      for (int mt = 0; mt < 4; ++mt)
#pragma unroll
        for (int nt = 0; nt < 4; ++nt)
          acc[mt][nt] = bmfma(af[mt], bf[nt], acc[mt][nt]);
    }
    __syncthreads();
  }
}

// ---- fused pointwise GEMMs for q,k,v ---------------------------------------
__global__ __launch_bounds__(256) void pw_gemm_kernel(
    const unsigned short* __restrict__ wqm, const unsigned short* __restrict__ wkm,
    const unsigned short* __restrict__ wvm,
    const unsigned short* __restrict__ yq, const unsigned short* __restrict__ yk,
    const unsigned short* __restrict__ yv,
    const float* __restrict__ qb, const float* __restrict__ kb, const float* __restrict__ vb,
    unsigned short* __restrict__ qT, unsigned short* __restrict__ kT,
    unsigned short* __restrict__ vvo) {
  int z = blockIdx.z, t = z >> 5, b = z & 31;
  const unsigned short* W = (t == 0) ? wqm : (t == 1) ? wkm : wvm;
  const unsigned short* Y = ((t == 0) ? yq : (t == 1) ? yk : yv) + (size_t)b * NL * NC;
  const float* bias = (t == 0) ? qb : (t == 1) ? kb : vb;
  unsigned short* out = (t == 0) ? qT : (t == 1) ? kT : vvo;
  __shared__ __attribute__((aligned(16))) unsigned short buf[16384];  // 32KB
  unsigned short* lA = buf;
  unsigned short* lB = buf + 8192;
  int m0 = blockIdx.y * 128, n0 = blockIdx.x * 128;
  float4v acc[4][4];
#pragma unroll
  for (int i = 0; i < 4; ++i)
#pragma unroll
    for (int j = 0; j < 4; ++j) acc[i][j] = (float4v){0.f, 0.f, 0.f, 0.f};
  gemm_core_bk64(W, Y, lA, lB, acc, m0, n0);
  int tid = threadIdx.x;
  int lane = tid & 63, quad = lane >> 4, l15 = lane & 15;
  int wave = tid >> 6, wr = wave >> 1, wc = wave & 1;
  if (t < 2) {
    // bounce through LDS: buf as [2 h][128 n][64 d] -> 16B-coalesced stores
#pragma unroll
    for (int mt = 0; mt < 4; ++mt) {
      int mloc = wr * 64 + mt * 16 + quad * 4;
#pragma unroll
      for (int nt = 0; nt < 4; ++nt) {
        int nloc = wc * 64 + nt * 16 + l15;
#pragma unroll
        for (int r = 0; r < 4; ++r) {
          int ml = mloc + r;
          buf[(ml >> 6) * 8192 + nloc * 64 + (ml & 63)] = f2b(acc[mt][nt][r] + bias[m0 + ml]);
        }
      }
    }
    __syncthreads();
#pragma unroll
    for (int it = 0; it < 8; ++it) {
      int cc = tid + it * 256;
      int hloc = cc >> 10, l = (cc >> 3) & 127, dc = cc & 7;
      short8 vd = *(const short8*)(buf + hloc * 8192 + l * 64 + dc * 8);
      *(short8*)(out + (((size_t)b * NH + (m0 >> 6) + hloc) * NL + n0 + l) * NDK + dc * 8) = vd;
    }
  } else {
#pragma unroll
    for (int mt = 0; mt < 4; ++mt)
#pragma unroll
      for (int nt = 0; nt < 4; ++nt) {
        int n = n0 + wc * 64 + nt * 16 + l15;
#pragma unroll
        for (int r = 0; r < 4; ++r) {
          int m = m0 + wr * 64 + mt * 16 + quad * 4 + r;
          out[((size_t)b * NC + m) * NL + n] = f2b(acc[mt][nt][r] + bias[m]);
        }
      }
  }
}

// ---- flash attention: j-tiles of 128, K staged in LDS, online softmax ------
__global__ __launch_bounds__(256) void attn_kernel(
    const unsigned short* __restrict__ qT,  // (B,H,L,DK)
    const unsigned short* __restrict__ kT,  // (B,H,L,DK)
    const unsigned short* __restrict__ vv,  // (B,C,L)
    unsigned short* __restrict__ AO) {      // (B,C,L)
  int i0 = blockIdx.x * 64, h = blockIdx.y, b = blockIdx.z;
  int tid = threadIdx.x, wave = tid >> 6, lane = tid & 63, quad = lane >> 4, l15 = lane & 15;
  __shared__ __attribute__((aligned(16))) unsigned short K0[128 * 32];  // j x d(0..31)
  __shared__ __attribute__((aligned(16))) unsigned short K1[128 * 32];  // j x d(32..63)
  __shared__ __attribute__((aligned(16))) unsigned short Pt[64 * 128];  // i x j, 16-chunk swizzle
  __shared__ float alpha_s[64];
  __shared__ float linv_s[64];
  const unsigned short* qh = qT + (size_t)(b * NH + h) * NL * NDK;
  const unsigned short* kh = kT + (size_t)(b * NH + h) * NL * NDK;
  const unsigned short* vh = vv + ((size_t)b * NC + h * NDK) * NL;
  int iw = i0 + wave * 16;
  short8 a0 = *(const short8*)(qh + (size_t)(iw + l15) * NDK + quad * 8);
  short8 a1 = *(const short8*)(qh + (size_t)(iw + l15) * NDK + 32 + quad * 8);
  int dwv = wave * 16;
  const unsigned short* vrow = vh + (size_t)(dwv + l15) * NL;
  // K staging: tile 128 j x 32 d per half; chunks cc = tid, tid+256
  const unsigned short* gka = kh + (size_t)(tid >> 2) * NDK + (tid & 3) * 8;
  const unsigned short* gkb = kh + (size_t)(64 + (tid >> 2)) * NDK + (tid & 3) * 8;
  unsigned short* dK0a = K0 + tid * 8;
  unsigned short* dK0b = K0 + (tid + 256) * 8;
  unsigned short* dK1a = K1 + tid * 8;
  unsigned short* dK1b = K1 + (tid + 256) * 8;
  int prow = wave * 16 + quad * 4;
  float m_run[4] = {-1e30f, -1e30f, -1e30f, -1e30f};
  float l_run[4] = {0.f, 0.f, 0.f, 0.f};
  float4v o[4];
#pragma unroll
  for (int i = 0; i < 4; ++i) o[i] = (float4v){0.f, 0.f, 0.f, 0.f};

  for (int jt = 0; jt < 4; ++jt) {
    size_t j0 = (size_t)jt * 128;
    gld16(gka + j0 * NDK, dK0a);
    gld16(gkb + j0 * NDK, dK0b);
    gld16(gka + j0 * NDK + 32, dK1a);
    gld16(gkb + j0 * NDK + 32, dK1b);
    __syncthreads();
    // S tile: 16 i-rows (this wave) x 128 j
    float4v s[8];
#pragma unroll
    for (int n4 = 0; n4 < 8; ++n4) {
      short8 kb0 = *(const short8*)(K0 + (n4 * 16 + l15) * 32 + quad * 8);
      short8 kb1 = *(const short8*)(K1 + (n4 * 16 + l15) * 32 + quad * 8);
      float4v acc = {0.f, 0.f, 0.f, 0.f};
      acc = bmfma(a0, kb0, acc);
      acc = bmfma(a1, kb1, acc);
      s[n4] = acc;
    }
    float al[4];
#pragma unroll
    for (int r = 0; r < 4; ++r) {
      float mx = -1e30f;
#pragma unroll
      for (int n4 = 0; n4 < 8; ++n4) mx = fmaxf(mx, s[n4][r]);
      mx = fmaxf(mx, __shfl_xor(mx, 1));
      mx = fmaxf(mx, __shfl_xor(mx, 2));
      mx = fmaxf(mx, __shfl_xor(mx, 4));
      mx = fmaxf(mx, __shfl_xor(mx, 8));
      mx *= 0.125f;
      float mn = fmaxf(m_run[r], mx);
      al[r] = __expf(m_run[r] - mn);
      m_run[r] = mn;
      float sum = 0.f;
#pragma unroll
      for (int n4 = 0; n4 < 8; ++n4) {
        float p = __expf(s[n4][r] * 0.125f - mn);
        s[n4][r] = p;
        sum += p;
      }
      sum += __shfl_xor(sum, 1);
      sum += __shfl_xor(sum, 2);
      sum += __shfl_xor(sum, 4);
      sum += __shfl_xor(sum, 8);
      l_run[r] = l_run[r] * al[r] + sum;
    }
    // write P (bf16, 16-chunk XOR swizzle) + alpha
#pragma unroll
    for (int n4 = 0; n4 < 8; ++n4)
#pragma unroll
      for (int r = 0; r < 4; ++r) {
        int row = prow + r, col = n4 * 16 + l15;
        int gc = col >> 3;
        Pt[row * 128 + (((gc ^ (row & 15)) << 3) | (col & 7))] = f2b(s[n4][r]);
      }
    if (l15 == 0) {
#pragma unroll
      for (int r = 0; r < 4; ++r) alpha_s[prow + r] = al[r];
    }
    __syncthreads();
    // PV: O(d,i) += V(d,j) P(i,j); this wave owns d-slice [16w,16w+16)
    short8 av[4];
#pragma unroll
    for (int ks = 0; ks < 4; ++ks)
      av[ks] = *(const short8*)(vrow + j0 + ks * 32 + quad * 8);
#pragma unroll
    for (int nt = 0; nt < 4; ++nt) {
      int rI = nt * 16 + l15;
      float aR = alpha_s[rI];
      o[nt][0] *= aR; o[nt][1] *= aR; o[nt][2] *= aR; o[nt][3] *= aR;
#pragma unroll
      for (int ks = 0; ks < 4; ++ks) {
        int slot = (ks * 4 + quad) ^ (rI & 15);
        short8 pb = *(const short8*)(Pt + rI * 128 + slot * 8);
        o[nt] = bmfma(av[ks], pb, o[nt]);
      }
    }
  }
  if (l15 == 0) {
#pragma unroll
    for (int r = 0; r < 4; ++r) linv_s[prow + r] = 1.0f / l_run[r];
  }
  __syncthreads();
#pragma unroll
  for (int nt = 0; nt < 4; ++nt) {
    float li = linv_s[nt * 16 + l15];
#pragma unroll
    for (int r = 0; r < 4; ++r) {
      int d = dwv + quad * 4 + r;
      AO[((size_t)b * NC + h * NDK + d) * NL + i0 + nt * 16 + l15] = f2b(o[nt][r] * li);
    }
  }
}

// ---- final projection GEMM (fp32 out) --------------------------------------
__global__ __launch_bounds__(256) void final_gemm_kernel(
    const unsigned short* __restrict__ AO, const unsigned short* __restrict__ W,
    const float* __restrict__ bias, float* __restrict__ out) {
  int b = blockIdx.z;
  __shared__ __attribute__((aligned(16))) unsigned short buf[16384];
  unsigned short* lA = buf;
  unsigned short* lB = buf + 8192;
  int m0 = blockIdx.y * 128, n0 = blockIdx.x * 128;
  float4v acc[4][4];
#pragma unroll
  for (int i = 0; i < 4; ++i)
#pragma unroll
    for (int j = 0; j < 4; ++j) acc[i][j] = (float4v){0.f, 0.f, 0.f, 0.f};
  gemm_core_bk64(AO + (size_t)b * 512 * 512, W, lA, lB, acc, m0, n0);
  int lane = threadIdx.x & 63, quad = lane >> 4, l15 = lane & 15;
  int wave = threadIdx.x >> 6, wr = wave >> 1, wc = wave & 1;
#pragma unroll
  for (int mt = 0; mt < 4; ++mt)
#pragma unroll
    for (int nt = 0; nt < 4; ++nt) {
      int n = n0 + wc * 64 + nt * 16 + l15;
      float bn = bias[n];
#pragma unroll
      for (int r = 0; r < 4; ++r) {
        int m = m0 + wr * 64 + mt * 16 + quad * 4 + r;
        out[((size_t)b * 512 + m) * 512 + n] = acc[mt][nt][r] + bn;
      }
    }
}

extern "C" void kernel_launch(void* const* d_in, const int* in_sizes, int n_in,
                              void* d_out, int out_size, void* d_ws, size_t ws_size,
                              hipStream_t stream) {
  (void)in_sizes; (void)n_in; (void)out_size; (void)ws_size;
  const float* query  = (const float*)d_in[0];
  const float* key    = (const float*)d_in[1];
  const float* value  = (const float*)d_in[2];
  const float* pos    = (const float*)d_in[3];
  const float* proj_w = (const float*)d_in[4];
  const float* proj_b = (const float*)d_in[5];
  const float* q_dw_w = (const float*)d_in[6];
  const float* q_dw_b = (const float*)d_in[7];
  const float* q_pw_w = (const float*)d_in[8];
  const float* q_pw_b = (const float*)d_in[9];
  const float* k_dw_w = (const float*)d_in[10];
  const float* k_dw_b = (const float*)d_in[11];
  const float* k_pw_w = (const float*)d_in[12];
  const float* k_pw_b = (const float*)d_in[13];
  const float* v_dw_w = (const float*)d_in[14];
  const float* v_dw_b = (const float*)d_in[15];
  const float* v_pw_w = (const float*)d_in[16];
  const float* v_pw_b = (const float*)d_in[17];

  char* ws = (char*)d_ws;
  const size_t WMAT = (size_t)512 * 512 * 2;     // 512 KB
  const size_t TEN  = (size_t)NB * NC * NL * 2;  // 16 MB
  unsigned short* wq  = (unsigned short*)(ws);
  unsigned short* wk  = (unsigned short*)(ws + WMAT);
  unsigned short* wv  = (unsigned short*)(ws + 2 * WMAT);
  unsigned short* wp  = (unsigned short*)(ws + 3 * WMAT);
  unsigned short* yq  = (unsigned short*)(ws + 4 * WMAT);
  unsigned short* yk  = (unsigned short*)(ws + 4 * WMAT + TEN);
  unsigned short* yv  = (unsigned short*)(ws + 4 * WMAT + 2 * TEN);
  unsigned short* qT  = (unsigned short*)(ws + 4 * WMAT + 3 * TEN);
  unsigned short* kT  = (unsigned short*)(ws + 4 * WMAT + 4 * TEN);
  unsigned short* vvb = (unsigned short*)(ws + 4 * WMAT + 5 * TEN);
  unsigned short* AO  = yq;  // yq fully consumed by pw(q) before attention writes
  // posconv buffers live in qT's region: consumed by dw BEFORE pw writes qT
  float* pqc = (float*)qT;                         // 1 MB
  float* pkc = (float*)(ws + 4 * WMAT + 3 * TEN + (size_t)NL * NC * 4);  // 1 MB

  cvt4_kernel<<<dim3(256, 4), 256, 0, stream>>>(q_pw_w, k_pw_w, v_pw_w, proj_w, wq, wk, wv, wp);

  posconv_kernel<<<dim3(512, 2), 256, 0, stream>>>(pos, q_dw_w, q_dw_b, k_dw_w, k_dw_b, pqc, pkc);

  dw_kernel<<<dim3(8, 8, 96), 256, 0, stream>>>(
      query, key, value, pqc, pkc, q_dw_w, k_dw_w, v_dw_w, v_dw_b, yq, yk, yv);

  pw_gemm_kernel<<<dim3(4, 4, 96), 256, 0, stream>>>(
      wq, wk, wv, yq, yk, yv, q_pw_b, k_pw_b, v_pw_b, qT, kT, vvb);

  attn_kernel<<<dim3(8, 8, 32), 256, 0, stream>>>(qT, kT, vvb, AO);

  final_gemm_kernel<<<dim3(4, 4, 32), 256, 0, stream>>>(AO, wp, proj_b, (float*)d_out);
}